// Round 16
// baseline (74.294 us; speedup 1.0000x reference)
//
#include <hip/hip_runtime.h>

typedef unsigned short u16;
typedef unsigned int u32;
using half8 = __attribute__((ext_vector_type(8))) _Float16;
using f32x4 = __attribute__((ext_vector_type(4))) float;
using i32x4 = __attribute__((ext_vector_type(4))) int;

#define NB 8
#define NN 2048

__device__ __forceinline__ u16 f2h(float f) {
    _Float16 h = (_Float16)f;                     // v_cvt_f16_f32 (RNE)
    union { _Float16 h; u16 u; } cvt; cvt.h = h;
    return cvt.u;
}

// K1: h = x@W ; es/ed ; hT fp16, TRANSPOSED [b][d][n]. (no softmax shift:
// shift-invariance is exact; zero shift is range-safe for these magnitudes)
__global__ __launch_bounds__(256, 2) void gat_k1(
    const float* __restrict__ x, const float* __restrict__ W, const float* __restrict__ a,
    u16* __restrict__ hT,
    float* __restrict__ es, float* __restrict__ ed)
{
    const int tid  = threadIdx.x;
    const int lane = tid & 63;
    const int wid  = tid >> 6;
    const int rowbase = blockIdx.x * 16;          // global row in [0, B*N)
    const int b    = rowbase >> 11;
    const int col0 = rowbase & 2047;

    __shared__ float xs[16][64];
    __shared__ u16 lh[64][20];     // +4 pad

    {
        const float4 v = *reinterpret_cast<const float4*>(x + (size_t)rowbase * 64 + tid * 4);
        *reinterpret_cast<float4*>(&xs[0][0] + tid * 4) = v;
    }

    float Wc[64];
#pragma unroll
    for (int k = 0; k < 64; ++k) Wc[k] = W[k * 64 + lane];
    const float asrc = a[lane], adst = a[64 + lane];
    __syncthreads();

#pragma unroll
    for (int r = 0; r < 4; ++r) {
        const int row = wid * 4 + r;
        float acc = 0.f;
#pragma unroll
        for (int kq = 0; kq < 16; ++kq) {
            const float4 xv = *reinterpret_cast<const float4*>(&xs[row][kq * 4]);
            acc = fmaf(xv.x, Wc[kq * 4 + 0], acc);
            acc = fmaf(xv.y, Wc[kq * 4 + 1], acc);
            acc = fmaf(xv.z, Wc[kq * 4 + 2], acc);
            acc = fmaf(xv.w, Wc[kq * 4 + 3], acc);
        }
        float vs = acc * asrc, vd = acc * adst;
#pragma unroll
        for (int off = 32; off; off >>= 1) {
            vs += __shfl_xor(vs, off, 64);
            vd += __shfl_xor(vd, off, 64);
        }
        if (lane == 0) { es[rowbase + row] = vs; ed[rowbase + row] = vd; }
        lh[lane][row] = f2h(acc);
    }
    __syncthreads();

    {
        const int d = tid >> 2, part = tid & 3;
        u32 h0 = lh[d][part*4+0] | ((u32)lh[d][part*4+1] << 16);
        u32 h1 = lh[d][part*4+2] | ((u32)lh[d][part*4+3] << 16);
        size_t goff = (size_t)(b * 64 + d) * 2048 + col0 + part * 4;
        *reinterpret_cast<uint2*>(hT + goff) = make_uint2(h0, h1);
    }
}

#define NTL(p) __builtin_nontemporal_load(reinterpret_cast<const i32x4*>(p))

// K3: block = 16 rows x FULL 2048 j; 4 waves = 4 j-quarters (512 cols each).
// NO barriers in the sweep: hT read direct from L2 (batch pinned to XCD),
// adjacency nontemporal per-lane, ed direct. One barrier for the epilogue.
__global__ __launch_bounds__(256, 4) void gat_k3(
    const int* __restrict__ adj,
    const u16* __restrict__ hT,
    const float* __restrict__ es, const float* __restrict__ ed,
    float* __restrict__ out)
{
    const int g = blockIdx.x;
    const int b  = g & 7;                 // batch -> XCD pinned
    const int it = g >> 3;                // 128 row-tiles of 16 per batch
    const int tid  = threadIdx.x;
    const int lane = tid & 63;
    const int jq   = tid >> 6;            // wave = j-quarter 0..3
    const int li   = lane & 15;           // A/C row, B d-col
    const int lg   = lane >> 4;           // k-group
    const int gr0  = b * 2048 + it * 16;  // global row base

    const float es_i = es[gr0 + li];
    const float L2E  = 1.44269504088896f;

    const int* __restrict__ arow =
        adj + (size_t)(gr0 + li) * 2048 + jq * 512 + lg * 8;
    const float* __restrict__ edq = ed + b * 2048 + jq * 512 + lg * 8;
    const u16* __restrict__ bh = hT + (size_t)(b * 64 + li) * 2048 + jq * 512 + lg * 8;

    f32x4 acc0 = {0.f,0.f,0.f,0.f}, acc1 = {0.f,0.f,0.f,0.f};
    f32x4 acc2 = {0.f,0.f,0.f,0.f}, acc3 = {0.f,0.f,0.f,0.f};
    float rs = 0.f;

#pragma unroll
    for (int kk = 0; kk < 16; ++kk) {     // 16 windows of 32 cols, no barriers
        const int jo = kk * 32;
        const i32x4 a0 = NTL(arow + jo);
        const i32x4 a1 = NTL(arow + jo + 4);
        const float4 e0 = *reinterpret_cast<const float4*>(edq + jo);
        const float4 e1 = *reinterpret_cast<const float4*>(edq + jo + 4);
        const float ev[8] = {e0.x,e0.y,e0.z,e0.w,e1.x,e1.y,e1.z,e1.w};
        const int av[8] = {a0[0],a0[1],a0[2],a0[3],a1[0],a1[1],a1[2],a1[3]};

        float pe[8];
#pragma unroll
        for (int q = 0; q < 8; ++q) {
            const float tt = es_i + ev[q];
            const float eL = fmaxf(tt, 0.2f * tt);
            const float p  = __builtin_amdgcn_exp2f(eL * L2E);
            pe[q] = av[q] ? p : 0.f;
        }
        rs += ((pe[0]+pe[1]) + (pe[2]+pe[3])) + ((pe[4]+pe[5]) + (pe[6]+pe[7]));

        half8 pa;
#pragma unroll
        for (int q = 0; q < 8; ++q) pa[q] = (_Float16)pe[q];

        half8 f0 = *reinterpret_cast<const half8*>(bh + (size_t)0*16*2048 + jo);
        half8 f1 = *reinterpret_cast<const half8*>(bh + (size_t)1*16*2048 + jo);
        half8 f2 = *reinterpret_cast<const half8*>(bh + (size_t)2*16*2048 + jo);
        half8 f3 = *reinterpret_cast<const half8*>(bh + (size_t)3*16*2048 + jo);

        acc0 = __builtin_amdgcn_mfma_f32_16x16x32_f16(pa, f0, acc0, 0, 0, 0);
        acc1 = __builtin_amdgcn_mfma_f32_16x16x32_f16(pa, f1, acc1, 0, 0, 0);
        acc2 = __builtin_amdgcn_mfma_f32_16x16x32_f16(pa, f2, acc2, 0, 0, 0);
        acc3 = __builtin_amdgcn_mfma_f32_16x16x32_f16(pa, f3, acc3, 0, 0, 0);
    }

    // ---- epilogue: combine 4 jq in LDS, normalize, write out ----
    rs += __shfl_xor(rs, 16, 64);
    rs += __shfl_xor(rs, 32, 64);

    __shared__ float accL[4][16][64];     // 16 KB
    __shared__ float rsL[4][16];
    if (lane < 16) rsL[jq][li] = rs;
    {
        f32x4 accs[4] = {acc0, acc1, acc2, acc3};
#pragma unroll
        for (int dt = 0; dt < 4; ++dt)
#pragma unroll
            for (int r = 0; r < 4; ++r)
                accL[jq][4 * lg + r][dt * 16 + li] = accs[dt][r];
    }
    __syncthreads();

    {
        const int r  = tid >> 4;          // 0..15
        const int d0 = (tid & 15) * 4;
        const float s = (rsL[0][r] + rsL[1][r]) + (rsL[2][r] + rsL[3][r]);
        const float inv = 1.0f / s;
        float4 o;
        float* o4 = &o.x;
#pragma unroll
        for (int e = 0; e < 4; ++e) {
            float v = 0.f;
#pragma unroll
            for (int cc = 0; cc < 4; ++cc)
                v += accL[cc][r][d0 + e];
            o4[e] = v * inv;
        }
        *reinterpret_cast<float4*>(out + ((size_t)(gr0 + r) * 64 + d0)) = o;
    }
}

extern "C" void kernel_launch(void* const* d_in, const int* in_sizes, int n_in,
                              void* d_out, int out_size, void* d_ws, size_t ws_size,
                              hipStream_t stream)
{
    const float* x   = (const float*)d_in[0];
    const int*   adj = (const int*)d_in[1];
    const float* W   = (const float*)d_in[2];
    const float* a   = (const float*)d_in[3];
    float* out = (float*)d_out;

    char* ws = (char*)d_ws;
    size_t off = 0;
    auto carve = [&](size_t bytes) -> void* {
        void* p = ws + off;
        off += (bytes + 255) & ~(size_t)255;
        return p;
    };
    u16*   hT = (u16*)  carve((size_t)NB * 64 * NN * 2);
    float* es = (float*)carve((size_t)NB * NN * 4);
    float* ed = (float*)carve((size_t)NB * NN * 4);
    (void)ws_size; (void)in_sizes; (void)n_in; (void)out_size;

    gat_k1<<<NB * NN / 16, 256, 0, stream>>>(x, W, a, hT, es, ed);
    gat_k3<<<NB * NN / 16, 256, 0, stream>>>(adj, hT, es, ed, out);
}

// Round 17
// 47.443 us; speedup vs baseline: 1.5660x; 1.5660x over previous
//
#include <hip/hip_runtime.h>

typedef unsigned short u16;
typedef unsigned int u32;
using short8 = __attribute__((ext_vector_type(8))) short;
using half8  = __attribute__((ext_vector_type(8))) _Float16;
using f32x4  = __attribute__((ext_vector_type(4))) float;

#define NB 8
#define NN 2048

#define ROWB   144                  // 64j*2B + 16 pad
#define SLAB   9216                 // 64 d-rows x 144 B (one 64-col window)
#define ED_OFF 18432                // after 2 wave slabs
#define SMEM_SZ 26624               // 2*9216 + 8192 -> 6 blocks/CU

__device__ __forceinline__ u16 f2h(float f) {
    _Float16 h = (_Float16)f;
    union { _Float16 h; u16 u; } cvt; cvt.h = h;
    return cvt.u;
}

// K1: h = x@W ; es/ed ; hT fp16 transposed [b][d][n]. (no softmax shift:
// shift-invariance exact; zero shift range-safe for these magnitudes)
__global__ __launch_bounds__(256, 2) void gat_k1(
    const float* __restrict__ x, const float* __restrict__ W, const float* __restrict__ a,
    u16* __restrict__ hT,
    float* __restrict__ es, float* __restrict__ ed)
{
    const int tid  = threadIdx.x;
    const int lane = tid & 63;
    const int wid  = tid >> 6;
    const int rowbase = blockIdx.x * 16;
    const int b    = rowbase >> 11;
    const int col0 = rowbase & 2047;

    __shared__ float xs[16][64];
    __shared__ u16 lh[64][20];

    {
        const float4 v = *reinterpret_cast<const float4*>(x + (size_t)rowbase * 64 + tid * 4);
        *reinterpret_cast<float4*>(&xs[0][0] + tid * 4) = v;
    }

    float Wc[64];
#pragma unroll
    for (int k = 0; k < 64; ++k) Wc[k] = W[k * 64 + lane];
    const float asrc = a[lane], adst = a[64 + lane];
    __syncthreads();

#pragma unroll
    for (int r = 0; r < 4; ++r) {
        const int row = wid * 4 + r;
        float acc = 0.f;
#pragma unroll
        for (int kq = 0; kq < 16; ++kq) {
            const float4 xv = *reinterpret_cast<const float4*>(&xs[row][kq * 4]);
            acc = fmaf(xv.x, Wc[kq * 4 + 0], acc);
            acc = fmaf(xv.y, Wc[kq * 4 + 1], acc);
            acc = fmaf(xv.z, Wc[kq * 4 + 2], acc);
            acc = fmaf(xv.w, Wc[kq * 4 + 3], acc);
        }
        float vs = acc * asrc, vd = acc * adst;
#pragma unroll
        for (int off = 32; off; off >>= 1) {
            vs += __shfl_xor(vs, off, 64);
            vd += __shfl_xor(vd, off, 64);
        }
        if (lane == 0) { es[rowbase + row] = vs; ed[rowbase + row] = vd; }
        lh[lane][row] = f2h(acc);
    }
    __syncthreads();

    {
        const int d = tid >> 2, part = tid & 3;
        u32 h0 = lh[d][part*4+0] | ((u32)lh[d][part*4+1] << 16);
        u32 h1 = lh[d][part*4+2] | ((u32)lh[d][part*4+3] << 16);
        size_t goff = (size_t)(b * 64 + d) * 2048 + col0 + part * 4;
        *reinterpret_cast<uint2*>(hT + goff) = make_uint2(h0, h1);
    }
}

// K3: block = 2 independent waves; wave = 16 rows x FULL 2048 j, 32 windows
// of 64 j. Wave-private single-buffered hT slab in LDS -> ZERO barriers in
// the sweep (same-wave ds ordering via lgkmcnt). One prologue barrier (ed).
__global__ __launch_bounds__(128, 2) void gat_k3(
    const int* __restrict__ adj,
    const u16* __restrict__ hT,
    const float* __restrict__ es, const float* __restrict__ ed,
    float* __restrict__ out)
{
    __shared__ char smem[SMEM_SZ] __attribute__((aligned(16)));
    const int g  = blockIdx.x;
    const int b  = g & 7;                 // batch -> XCD pinned
    const int it = g >> 3;                // 64 row-pairs per batch
    const int tid  = threadIdx.x;
    const int lane = tid & 63;
    const int w    = tid >> 6;            // wave 0..1
    const int li   = lane & 15;
    const int lg   = lane >> 4;
    const int gr0  = b * 2048 + it * 32 + w * 16;   // this wave's row base

    // ---- stage ed (8 KB) once; one-time barrier ----
    {
        float4* edL = (float4*)(smem + ED_OFF);
        const float4* eds = (const float4*)(ed + b * 2048);
#pragma unroll
        for (int rep = 0; rep < 4; ++rep)
            edL[rep * 128 + tid] = eds[rep * 128 + tid];
    }

    const float es_i = es[gr0 + li];
    const float L2E  = 1.44269504088896f;

    const int* __restrict__ arow = adj + (size_t)(gr0 + li) * 2048 + lg * 8;

    // wave-private slab; lane stages d-rows (lane>>1) and 32+(lane>>1)
    char* slab = smem + w * SLAB;
    const int dd = lane >> 1, jp = lane & 1;
    const u16* __restrict__ hrow0 = hT + (size_t)(b * 64 + dd) * 2048 + jp * 32;
    const u16* __restrict__ hrow1 = hT + (size_t)(b * 64 + 32 + dd) * 2048 + jp * 32;
    const int swo0 = dd * ROWB + jp * 64;
    const int swo1 = (32 + dd) * ROWB + jp * 64;

    // ---- prologue: stage window 0; adj window 0 ----
    {
        short8 s0 = *reinterpret_cast<const short8*>(hrow0);
        short8 s1 = *reinterpret_cast<const short8*>(hrow0 + 8);
        short8 s2 = *reinterpret_cast<const short8*>(hrow0 + 16);
        short8 s3 = *reinterpret_cast<const short8*>(hrow0 + 24);
        short8 s4 = *reinterpret_cast<const short8*>(hrow1);
        short8 s5 = *reinterpret_cast<const short8*>(hrow1 + 8);
        short8 s6 = *reinterpret_cast<const short8*>(hrow1 + 16);
        short8 s7 = *reinterpret_cast<const short8*>(hrow1 + 24);
        *reinterpret_cast<short8*>(slab + swo0)      = s0;
        *reinterpret_cast<short8*>(slab + swo0 + 16) = s1;
        *reinterpret_cast<short8*>(slab + swo0 + 32) = s2;
        *reinterpret_cast<short8*>(slab + swo0 + 48) = s3;
        *reinterpret_cast<short8*>(slab + swo1)      = s4;
        *reinterpret_cast<short8*>(slab + swo1 + 16) = s5;
        *reinterpret_cast<short8*>(slab + swo1 + 32) = s6;
        *reinterpret_cast<short8*>(slab + swo1 + 48) = s7;
    }
    int4 c0 = *reinterpret_cast<const int4*>(arow);
    int4 c1 = *reinterpret_cast<const int4*>(arow + 4);
    int4 c2 = *reinterpret_cast<const int4*>(arow + 32);
    int4 c3 = *reinterpret_cast<const int4*>(arow + 36);
    __syncthreads();   // ed visible; ONLY barrier before epilogue

    f32x4 acc0 = {0.f,0.f,0.f,0.f}, acc1 = {0.f,0.f,0.f,0.f};
    f32x4 acc2 = {0.f,0.f,0.f,0.f}, acc3 = {0.f,0.f,0.f,0.f};
    float rs = 0.f;
    const float* edq = (const float*)(smem + ED_OFF) + lg * 8;
    const int fo = li * ROWB + lg * 16;

#pragma unroll 2
    for (int kk = 0; kk < 32; ++kk) {
        const int jo = kk * 64;
        // prefetch next window (hT + adj) — no barriers, stays in flight
        short8 n0, n1, n2, n3, n4, n5, n6, n7;
        int4 m0, m1, m2, m3;
        if (kk < 31) {
            n0 = *reinterpret_cast<const short8*>(hrow0 + jo + 64);
            n1 = *reinterpret_cast<const short8*>(hrow0 + jo + 72);
            n2 = *reinterpret_cast<const short8*>(hrow0 + jo + 80);
            n3 = *reinterpret_cast<const short8*>(hrow0 + jo + 88);
            n4 = *reinterpret_cast<const short8*>(hrow1 + jo + 64);
            n5 = *reinterpret_cast<const short8*>(hrow1 + jo + 72);
            n6 = *reinterpret_cast<const short8*>(hrow1 + jo + 80);
            n7 = *reinterpret_cast<const short8*>(hrow1 + jo + 88);
            m0 = *reinterpret_cast<const int4*>(arow + jo + 64);
            m1 = *reinterpret_cast<const int4*>(arow + jo + 68);
            m2 = *reinterpret_cast<const int4*>(arow + jo + 96);
            m3 = *reinterpret_cast<const int4*>(arow + jo + 100);
        }

        half8 pa0, pa1;
        {
            const float4 e0 = *reinterpret_cast<const float4*>(edq + jo);
            const float4 e1 = *reinterpret_cast<const float4*>(edq + jo + 4);
            const float ev[8] = {e0.x,e0.y,e0.z,e0.w,e1.x,e1.y,e1.z,e1.w};
            const int av[8] = {c0.x,c0.y,c0.z,c0.w,c1.x,c1.y,c1.z,c1.w};
            float pe[8];
#pragma unroll
            for (int q = 0; q < 8; ++q) {
                const float tt = es_i + ev[q];
                const float eL = fmaxf(tt, 0.2f * tt);
                const float p  = __builtin_amdgcn_exp2f(eL * L2E);
                pe[q] = av[q] ? p : 0.f;
            }
            rs += ((pe[0]+pe[1]) + (pe[2]+pe[3])) + ((pe[4]+pe[5]) + (pe[6]+pe[7]));
#pragma unroll
            for (int q = 0; q < 8; ++q) pa0[q] = (_Float16)pe[q];
        }
        {
            const float4 e0 = *reinterpret_cast<const float4*>(edq + jo + 32);
            const float4 e1 = *reinterpret_cast<const float4*>(edq + jo + 36);
            const float ev[8] = {e0.x,e0.y,e0.z,e0.w,e1.x,e1.y,e1.z,e1.w};
            const int av[8] = {c2.x,c2.y,c2.z,c2.w,c3.x,c3.y,c3.z,c3.w};
            float pe[8];
#pragma unroll
            for (int q = 0; q < 8; ++q) {
                const float tt = es_i + ev[q];
                const float eL = fmaxf(tt, 0.2f * tt);
                const float p  = __builtin_amdgcn_exp2f(eL * L2E);
                pe[q] = av[q] ? p : 0.f;
            }
            rs += ((pe[0]+pe[1]) + (pe[2]+pe[3])) + ((pe[4]+pe[5]) + (pe[6]+pe[7]));
#pragma unroll
            for (int q = 0; q < 8; ++q) pa1[q] = (_Float16)pe[q];
        }

        half8 f0 = *reinterpret_cast<const half8*>(slab + 0 * 2304 + fo);
        half8 f1 = *reinterpret_cast<const half8*>(slab + 1 * 2304 + fo);
        half8 f2 = *reinterpret_cast<const half8*>(slab + 2 * 2304 + fo);
        half8 f3 = *reinterpret_cast<const half8*>(slab + 3 * 2304 + fo);
        half8 g0 = *reinterpret_cast<const half8*>(slab + 0 * 2304 + 64 + fo);
        half8 g1 = *reinterpret_cast<const half8*>(slab + 1 * 2304 + 64 + fo);
        half8 g2 = *reinterpret_cast<const half8*>(slab + 2 * 2304 + 64 + fo);
        half8 g3 = *reinterpret_cast<const half8*>(slab + 3 * 2304 + 64 + fo);

        acc0 = __builtin_amdgcn_mfma_f32_16x16x32_f16(pa0, f0, acc0, 0, 0, 0);
        acc1 = __builtin_amdgcn_mfma_f32_16x16x32_f16(pa0, f1, acc1, 0, 0, 0);
        acc2 = __builtin_amdgcn_mfma_f32_16x16x32_f16(pa0, f2, acc2, 0, 0, 0);
        acc3 = __builtin_amdgcn_mfma_f32_16x16x32_f16(pa0, f3, acc3, 0, 0, 0);
        acc0 = __builtin_amdgcn_mfma_f32_16x16x32_f16(pa1, g0, acc0, 0, 0, 0);
        acc1 = __builtin_amdgcn_mfma_f32_16x16x32_f16(pa1, g1, acc1, 0, 0, 0);
        acc2 = __builtin_amdgcn_mfma_f32_16x16x32_f16(pa1, g2, acc2, 0, 0, 0);
        acc3 = __builtin_amdgcn_mfma_f32_16x16x32_f16(pa1, g3, acc3, 0, 0, 0);

        if (kk < 31) {   // overwrite own slab; frag reads above already ordered
            *reinterpret_cast<short8*>(slab + swo0)      = n0;
            *reinterpret_cast<short8*>(slab + swo0 + 16) = n1;
            *reinterpret_cast<short8*>(slab + swo0 + 32) = n2;
            *reinterpret_cast<short8*>(slab + swo0 + 48) = n3;
            *reinterpret_cast<short8*>(slab + swo1)      = n4;
            *reinterpret_cast<short8*>(slab + swo1 + 16) = n5;
            *reinterpret_cast<short8*>(slab + swo1 + 32) = n6;
            *reinterpret_cast<short8*>(slab + swo1 + 48) = n7;
            c0 = m0; c1 = m1; c2 = m2; c3 = m3;
        }
    }

    // ---- epilogue (wave-local, no barrier): row sums, normalize, write ----
    rs += __shfl_xor(rs, 16, 64);
    rs += __shfl_xor(rs, 32, 64);      // all lanes: rs for their li-row
    float invr[4];
#pragma unroll
    for (int r = 0; r < 4; ++r)
        invr[r] = 1.0f / __shfl(rs, lg * 4 + r, 64);

    f32x4 accs[4] = {acc0, acc1, acc2, acc3};
#pragma unroll
    for (int dt = 0; dt < 4; ++dt)
#pragma unroll
        for (int r = 0; r < 4; ++r)
            out[(size_t)(gr0 + lg * 4 + r) * 64 + dt * 16 + li] = accs[dt][r] * invr[r];
}

extern "C" void kernel_launch(void* const* d_in, const int* in_sizes, int n_in,
                              void* d_out, int out_size, void* d_ws, size_t ws_size,
                              hipStream_t stream)
{
    const float* x   = (const float*)d_in[0];
    const int*   adj = (const int*)d_in[1];
    const float* W   = (const float*)d_in[2];
    const float* a   = (const float*)d_in[3];
    float* out = (float*)d_out;

    char* ws = (char*)d_ws;
    size_t off = 0;
    auto carve = [&](size_t bytes) -> void* {
        void* p = ws + off;
        off += (bytes + 255) & ~(size_t)255;
        return p;
    };
    u16*   hT = (u16*)  carve((size_t)NB * 64 * NN * 2);
    float* es = (float*)carve((size_t)NB * NN * 4);
    float* ed = (float*)carve((size_t)NB * NN * 4);
    (void)ws_size; (void)in_sizes; (void)n_in; (void)out_size;

    gat_k1<<<NB * NN / 16, 256, 0, stream>>>(x, W, a, hT, es, ed);
    gat_k3<<<NB * NN / 32, 128, 0, stream>>>(adj, hT, es, ed, out);
}

// Round 19
// 38.984 us; speedup vs baseline: 1.9058x; 1.2170x over previous
//
#include <hip/hip_runtime.h>

typedef unsigned short u16;
typedef unsigned int u32;
using short8 = __attribute__((ext_vector_type(8))) short;
using half8  = __attribute__((ext_vector_type(8))) _Float16;
using f32x4  = __attribute__((ext_vector_type(4))) float;

#define NB 8
#define NN 2048

// k3 LDS layout (bytes): ed[2048] | 2 bufs x 4 jq x slab
#define EDL_OFF   0        // float[2048] = 8192
#define DBUF_OFF  8192     // 2 x 36864 = 73728 ; end = 81920 (80 KB, 2 blk/CU)
#define ROWB      144      // 64j*2B + 16 pad (16B aligned)
#define SLAB_SZ   9216     // 64 d-rows x 144
#define BUFSTRIDE 36864    // 4 jq slabs
#define RSL_OFF   (DBUF_OFF + 32768)   // alias: after epilogue accL (32 KB)
#define SMEM_SZ   81920

__device__ __forceinline__ u16 f2h(float f) {
    _Float16 h = (_Float16)f;                     // v_cvt_f16_f32 (RNE)
    union { _Float16 h; u16 u; } cvt; cvt.h = h;
    return cvt.u;
}

// K1: h = x@W ; es/ed ; hT fp16, TRANSPOSED [b][d][n]. (no softmax shift:
// shift-invariance is exact; zero shift is range-safe for these magnitudes)
__global__ __launch_bounds__(256, 2) void gat_k1(
    const float* __restrict__ x, const float* __restrict__ W, const float* __restrict__ a,
    u16* __restrict__ hT,
    float* __restrict__ es, float* __restrict__ ed)
{
    const int tid  = threadIdx.x;
    const int lane = tid & 63;
    const int wid  = tid >> 6;
    const int rowbase = blockIdx.x * 16;          // global row in [0, B*N)
    const int b    = rowbase >> 11;
    const int col0 = rowbase & 2047;

    __shared__ float xs[16][64];
    __shared__ u16 lh[64][20];     // +4 pad

    {
        const float4 v = *reinterpret_cast<const float4*>(x + (size_t)rowbase * 64 + tid * 4);
        *reinterpret_cast<float4*>(&xs[0][0] + tid * 4) = v;
    }

    float Wc[64];
#pragma unroll
    for (int k = 0; k < 64; ++k) Wc[k] = W[k * 64 + lane];
    const float asrc = a[lane], adst = a[64 + lane];
    __syncthreads();

#pragma unroll
    for (int r = 0; r < 4; ++r) {
        const int row = wid * 4 + r;
        float acc = 0.f;
#pragma unroll
        for (int kq = 0; kq < 16; ++kq) {
            const float4 xv = *reinterpret_cast<const float4*>(&xs[row][kq * 4]);
            acc = fmaf(xv.x, Wc[kq * 4 + 0], acc);
            acc = fmaf(xv.y, Wc[kq * 4 + 1], acc);
            acc = fmaf(xv.z, Wc[kq * 4 + 2], acc);
            acc = fmaf(xv.w, Wc[kq * 4 + 3], acc);
        }
        float vs = acc * asrc, vd = acc * adst;
#pragma unroll
        for (int off = 32; off; off >>= 1) {
            vs += __shfl_xor(vs, off, 64);
            vd += __shfl_xor(vd, off, 64);
        }
        if (lane == 0) { es[rowbase + row] = vs; ed[rowbase + row] = vd; }
        lh[lane][row] = f2h(acc);
    }
    __syncthreads();

    {
        const int d = tid >> 2, part = tid & 3;
        u32 h0 = lh[d][part*4+0] | ((u32)lh[d][part*4+1] << 16);
        u32 h1 = lh[d][part*4+2] | ((u32)lh[d][part*4+3] << 16);
        size_t goff = (size_t)(b * 64 + d) * 2048 + col0 + part * 4;
        *reinterpret_cast<uint2*>(hT + goff) = make_uint2(h0, h1);
    }
}

// one 32-col softmax half: consumes adj regs AA,AB; emits pa (no shift)
#define SM_HALF(EOFF, AA, AB, PA)                                                 \
{                                                                                 \
    const float4 e0 = *reinterpret_cast<const float4*>(edq + (EOFF));             \
    const float4 e1 = *reinterpret_cast<const float4*>(edq + (EOFF) + 4);         \
    const float ev[8] = {e0.x,e0.y,e0.z,e0.w,e1.x,e1.y,e1.z,e1.w};                \
    const int av[8] = {AA.x,AA.y,AA.z,AA.w,AB.x,AB.y,AB.z,AB.w};                  \
    float pe[8];                                                                  \
    _Pragma("unroll")                                                             \
    for (int q = 0; q < 8; ++q) {                                                 \
        const float tt = es_i + ev[q];                                            \
        const float eL = fmaxf(tt, 0.2f * tt);                                    \
        const float p  = __builtin_amdgcn_exp2f(eL * L2E);                        \
        pe[q] = av[q] ? p : 0.f;                                                  \
    }                                                                             \
    rs += ((pe[0]+pe[1]) + (pe[2]+pe[3])) + ((pe[4]+pe[5]) + (pe[6]+pe[7]));      \
    _Pragma("unroll")                                                             \
    for (int q = 0; q < 8; ++q) PA[q] = (_Float16)pe[q];                          \
}

// one 64-col window; 2-deep adj ring. ORDER: hT(w+1) issue (pinned oldest) ->
// SM consumes A0..A3 -> refill A0..A3 for w+2 -> slab reads + MFMA -> ds_write
// (compiler auto-waits counted vmcnt: retires hT, adj ring stays in flight)
// -> lgkmcnt(0) -> RAW s_barrier (no vmcnt(0) drain, unlike __syncthreads).
#define WIN_STEP(WIN, A0, A1, A2, A3)                                             \
{                                                                                 \
    const int wo = (WIN) * 64;                                                    \
    short8 nh0 = {}, nh1 = {}, nh2 = {}, nh3 = {};                                \
    if ((WIN) < 7) {                                                              \
        nh0 = *reinterpret_cast<const short8*>(hT + gb + wo + 64);                \
        nh1 = *reinterpret_cast<const short8*>(hT + gb + wo + 72);                \
        nh2 = *reinterpret_cast<const short8*>(hT + gb + wo + 80);                \
        nh3 = *reinterpret_cast<const short8*>(hT + gb + wo + 88);                \
    }                                                                             \
    __builtin_amdgcn_sched_barrier(0);  /* hT issue pinned above adj refill */    \
    half8 pa0, pa1;                                                               \
    SM_HALF(wo,      A0, A1, pa0)                                                 \
    SM_HALF(wo + 32, A2, A3, pa1)                                                 \
    if ((WIN) < 6) {   /* refill AFTER consumption (R18 bug: was before) */       \
        A0 = *reinterpret_cast<const int4*>(arow + wo + 128);                     \
        A1 = *reinterpret_cast<const int4*>(arow + wo + 132);                     \
        A2 = *reinterpret_cast<const int4*>(arow + wo + 160);                     \
        A3 = *reinterpret_cast<const int4*>(arow + wo + 164);                     \
    }                                                                             \
    const char* slab = ((WIN) & 1) ? slabB : slabA;                               \
    half8 f0 = *reinterpret_cast<const half8*>(slab + fo);                        \
    half8 f1 = *reinterpret_cast<const half8*>(slab + 2304 + fo);                 \
    half8 f2 = *reinterpret_cast<const half8*>(slab + 4608 + fo);                 \
    half8 f3 = *reinterpret_cast<const half8*>(slab + 6912 + fo);                 \
    half8 g0 = *reinterpret_cast<const half8*>(slab + 64 + fo);                   \
    half8 g1 = *reinterpret_cast<const half8*>(slab + 64 + 2304 + fo);            \
    half8 g2 = *reinterpret_cast<const half8*>(slab + 64 + 4608 + fo);            \
    half8 g3 = *reinterpret_cast<const half8*>(slab + 64 + 6912 + fo);            \
    acc0 = __builtin_amdgcn_mfma_f32_16x16x32_f16(pa0, f0, acc0, 0, 0, 0);        \
    acc1 = __builtin_amdgcn_mfma_f32_16x16x32_f16(pa0, f1, acc1, 0, 0, 0);        \
    acc2 = __builtin_amdgcn_mfma_f32_16x16x32_f16(pa0, f2, acc2, 0, 0, 0);        \
    acc3 = __builtin_amdgcn_mfma_f32_16x16x32_f16(pa0, f3, acc3, 0, 0, 0);        \
    acc0 = __builtin_amdgcn_mfma_f32_16x16x32_f16(pa1, g0, acc0, 0, 0, 0);        \
    acc1 = __builtin_amdgcn_mfma_f32_16x16x32_f16(pa1, g1, acc1, 0, 0, 0);        \
    acc2 = __builtin_amdgcn_mfma_f32_16x16x32_f16(pa1, g2, acc2, 0, 0, 0);        \
    acc3 = __builtin_amdgcn_mfma_f32_16x16x32_f16(pa1, g3, acc3, 0, 0, 0);        \
    if ((WIN) < 7) {    /* compiler auto-waits counted vmcnt here */              \
        char* nslab = ((WIN) & 1) ? slabA : slabB;                                \
        *reinterpret_cast<short8*>(nslab + swoff)      = nh0;                     \
        *reinterpret_cast<short8*>(nslab + swoff + 16) = nh1;                     \
        *reinterpret_cast<short8*>(nslab + swoff + 32) = nh2;                     \
        *reinterpret_cast<short8*>(nslab + swoff + 48) = nh3;                     \
    }                                                                             \
    asm volatile("s_waitcnt lgkmcnt(0)" ::: "memory");                            \
    __builtin_amdgcn_sched_barrier(0);                                            \
    __builtin_amdgcn_s_barrier();       /* raw barrier: NO vmcnt(0) drain */      \
    __builtin_amdgcn_sched_barrier(0);                                            \
}

// K3: block = 32 rows x FULL 2048 j; 8 waves = 2 rg x 4 jq; 8 windows of 64 j
// per jq. Full row sum in-block -> direct normalized output write.
__global__ __launch_bounds__(512, 4) void gat_k3(
    const int* __restrict__ adj,
    const u16* __restrict__ hT,
    const float* __restrict__ es, const float* __restrict__ ed,
    float* __restrict__ out)
{
    __shared__ char smem[SMEM_SZ] __attribute__((aligned(16)));
    const int g = blockIdx.x;
    const int b     = g & 7;              // batch -> XCD pinned
    const int itile = g >> 3;             // 64 row-tiles of 32
    const int tid  = threadIdx.x;
    const int lane = tid & 63;
    const int w    = tid >> 6;            // 0..7
    const int rg   = w >> 2;              // row-group (16 rows)
    const int jq   = w & 3;               // j-quarter (512 cols)
    const int li   = lane & 15;
    const int lg   = lane >> 4;
    const int gr0  = b * 2048 + itile * 32;

    // ---- stage full ed row-chunk (2048 floats) ----
    {
        float* edL = (float*)(smem + EDL_OFF);
#pragma unroll
        for (int rep = 0; rep < 4; ++rep)
            edL[rep * 512 + tid] = ed[b * 2048 + rep * 512 + tid];
    }
    const float es_i = es[gr0 + rg * 16 + li];
    const float L2E  = 1.44269504088896f;

    const int* __restrict__ arow =
        adj + (size_t)(gr0 + rg * 16 + li) * 2048 + jq * 512 + lg * 8;

    // ---- hT staging: 2 waves per jq stage 64 d-rows; lane -> 64 B/window ----
    const int dd  = rg * 32 + (lane >> 1);        // d-row this lane stages
    const int jp  = lane & 1;
    const size_t gb = (size_t)(b * 64 + dd) * 2048 + jq * 512 + jp * 32;
    const int swoff = dd * ROWB + jp * 64;

    char* slabA = smem + DBUF_OFF + jq * SLAB_SZ;
    char* slabB = slabA + BUFSTRIDE;

    // ---- prologue: adj windows 0,1; hT window 0 ----
    int4 pA0 = *reinterpret_cast<const int4*>(arow);
    int4 pA1 = *reinterpret_cast<const int4*>(arow + 4);
    int4 pA2 = *reinterpret_cast<const int4*>(arow + 32);
    int4 pA3 = *reinterpret_cast<const int4*>(arow + 36);
    int4 pB0 = *reinterpret_cast<const int4*>(arow + 64);
    int4 pB1 = *reinterpret_cast<const int4*>(arow + 68);
    int4 pB2 = *reinterpret_cast<const int4*>(arow + 96);
    int4 pB3 = *reinterpret_cast<const int4*>(arow + 100);
    {
        short8 h0 = *reinterpret_cast<const short8*>(hT + gb);
        short8 h1 = *reinterpret_cast<const short8*>(hT + gb + 8);
        short8 h2 = *reinterpret_cast<const short8*>(hT + gb + 16);
        short8 h3 = *reinterpret_cast<const short8*>(hT + gb + 24);
        *reinterpret_cast<short8*>(slabA + swoff)      = h0;
        *reinterpret_cast<short8*>(slabA + swoff + 16) = h1;
        *reinterpret_cast<short8*>(slabA + swoff + 32) = h2;
        *reinterpret_cast<short8*>(slabA + swoff + 48) = h3;
    }
    __syncthreads();   // prologue: full drain once is fine

    f32x4 acc0 = {0.f,0.f,0.f,0.f}, acc1 = {0.f,0.f,0.f,0.f};
    f32x4 acc2 = {0.f,0.f,0.f,0.f}, acc3 = {0.f,0.f,0.f,0.f};
    float rs = 0.f;
    const float* edq = (const float*)(smem + EDL_OFF) + jq * 512 + lg * 8;
    const int fo = li * ROWB + lg * 16;

    WIN_STEP(0, pA0, pA1, pA2, pA3)
    WIN_STEP(1, pB0, pB1, pB2, pB3)
    WIN_STEP(2, pA0, pA1, pA2, pA3)
    WIN_STEP(3, pB0, pB1, pB2, pB3)
    WIN_STEP(4, pA0, pA1, pA2, pA3)
    WIN_STEP(5, pB0, pB1, pB2, pB3)
    WIN_STEP(6, pA0, pA1, pA2, pA3)
    WIN_STEP(7, pB0, pB1, pB2, pB3)

    // ---- epilogue: full in-block combine over 4 jq, normalize, write out ----
    rs += __shfl_xor(rs, 16, 64);
    rs += __shfl_xor(rs, 32, 64);
    float* rsL  = (float*)(smem + RSL_OFF);      // [4 jq][32 rows], alias
    float* accL = (float*)(smem + DBUF_OFF);     // [8 w][16][64] = 32 KB, alias
    if (lane < 16) rsL[jq * 32 + rg * 16 + li] = rs;
    {
        f32x4 accs[4] = {acc0, acc1, acc2, acc3};
#pragma unroll
        for (int dt = 0; dt < 4; ++dt)
#pragma unroll
            for (int r = 0; r < 4; ++r)
                accL[(w * 16 + 4 * lg + r) * 64 + dt * 16 + li] = accs[dt][r];
    }
    __syncthreads();

    {
        const int r  = tid >> 4;                  // 0..31
        const int d0 = (tid & 15) * 4;
        const int rgo = r >> 4, ri = r & 15;
        const float s = (rsL[0 * 32 + r] + rsL[1 * 32 + r])
                      + (rsL[2 * 32 + r] + rsL[3 * 32 + r]);
        const float inv = 1.0f / s;
        float4 o;
        float* o4 = &o.x;
#pragma unroll
        for (int e = 0; e < 4; ++e) {
            float v = 0.f;
#pragma unroll
            for (int cc = 0; cc < 4; ++cc)
                v += accL[((rgo * 4 + cc) * 16 + ri) * 64 + d0 + e];
            o4[e] = v * inv;
        }
        *reinterpret_cast<float4*>(out + ((size_t)(gr0 + r) * 64 + d0)) = o;
    }
}

extern "C" void kernel_launch(void* const* d_in, const int* in_sizes, int n_in,
                              void* d_out, int out_size, void* d_ws, size_t ws_size,
                              hipStream_t stream)
{
    const float* x   = (const float*)d_in[0];
    const int*   adj = (const int*)d_in[1];
    const float* W   = (const float*)d_in[2];
    const float* a   = (const float*)d_in[3];
    float* out = (float*)d_out;

    char* ws = (char*)d_ws;
    size_t off = 0;
    auto carve = [&](size_t bytes) -> void* {
        void* p = ws + off;
        off += (bytes + 255) & ~(size_t)255;
        return p;
    };
    u16*   hT = (u16*)  carve((size_t)NB * 64 * NN * 2);
    float* es = (float*)carve((size_t)NB * NN * 4);
    float* ed = (float*)carve((size_t)NB * NN * 4);
    (void)ws_size; (void)in_sizes; (void)n_in; (void)out_size;

    gat_k1<<<NB * NN / 16, 256, 0, stream>>>(x, W, a, hT, es, ed);
    gat_k3<<<NB * NN / 32, 512, 0, stream>>>(adj, hT, es, ed, out);
}